// Round 2
// baseline (131.204 us; speedup 1.0000x reference)
//
#include <hip/hip_runtime.h>

#define NDIM 1024
#define BDIM 128
#define TS 32
#define NT (NDIM / TS)                  // 32 tile-rows
#define NTILES (NT * (NT + 1) / 2)      // 528 upper-tri tiles

// ---------------- stage 1: per-tile partial sums ----------------
__global__ __launch_bounds__(256) void potts_stage1(
    const float* __restrict__ V,      // [B][N] row-major
    const float* __restrict__ W,      // [N][N] row-major
    float* __restrict__ partial)      // [NTILES][B]
{
    const int t = blockIdx.x;
    // decode linear upper-tri tile index -> (ti, tj), ti <= tj (scalar, <=32 iters)
    int ti = 0, rem = t;
    while (rem >= NT - ti) { rem -= NT - ti; ++ti; }
    const int tj = ti + rem;
    const int I0 = ti * TS, J0 = tj * TS;
    const bool diag = (ti == tj);

    __shared__ float wt[TS][TS];        // 4 KB W tile, diag-masked at load
    __shared__ float vI[TS][BDIM + 1];  // transposed V slices, padded
    __shared__ float vJ[TS][BDIM + 1];
    __shared__ float red[256];

    const int tid = threadIdx.x;

    // --- stage W tile via coalesced float4 VECTOR loads; mask diag lower part once
    {
        const int r  = tid >> 3;          // 0..31
        const int c4 = (tid & 7) * 4;     // 0,4,...,28
        float4 w4 = *(const float4*)(W + (size_t)(I0 + r) * NDIM + (J0 + c4));
        if (diag) {                        // triu: keep j >= i
            if (c4 + 0 < r) w4.x = 0.0f;
            if (c4 + 1 < r) w4.y = 0.0f;
            if (c4 + 2 < r) w4.z = 0.0f;
            if (c4 + 3 < r) w4.w = 0.0f;
        }
        *(float4*)(&wt[r][c4]) = w4;
    }

    // --- stage V slices transposed: coalesced global reads, conflict-free LDS
    for (int idx = tid; idx < TS * BDIM; idx += 256) {
        const int j = idx & (TS - 1);
        const int b = idx >> 5;
        vJ[j][b] = V[b * NDIM + J0 + j];
        vI[j][b] = V[b * NDIM + I0 + j];
    }
    __syncthreads();

    const int b = tid & (BDIM - 1);
    const int half = tid >> 7;            // wave-uniform at runtime

    float vj[TS];
#pragma unroll
    for (int j = 0; j < TS; ++j) vj[j] = vJ[j][b];

    float acc0 = 0.f, acc1 = 0.f, acc2 = 0.f, acc3 = 0.f;

#pragma unroll
    for (int ii = 0; ii < TS / 2; ++ii) {
        const int iloc = half * (TS / 2) + ii;
        const float vi = vI[iloc][b];
        const float q = 1.0f - vi;
        const float r = 2.0f * vi - 1.0f;
#pragma unroll
        for (int j = 0; j < TS; j += 4) {
            // wave-uniform address -> LDS broadcast, conflict-free, overlaps VALU
            const float4 w4 = *(const float4*)(&wt[iloc][j]);
            acc0 = fmaf(w4.x, fmaf(r, vj[j + 0], q), acc0);
            acc1 = fmaf(w4.y, fmaf(r, vj[j + 1], q), acc1);
            acc2 = fmaf(w4.z, fmaf(r, vj[j + 2], q), acc2);
            acc3 = fmaf(w4.w, fmaf(r, vj[j + 3], q), acc3);
        }
    }

    const float acc = (acc0 + acc1) + (acc2 + acc3);

    red[tid] = acc;
    __syncthreads();
    if (tid < BDIM) {
        partial[t * BDIM + tid] = red[tid] + red[tid + BDIM];  // coalesced 512 B
    }
}

// ---------------- stage 2: reduce tiles -> out[b], lanes across b ----------------
__global__ __launch_bounds__(256) void potts_stage2(
    const float* __restrict__ partial, float* __restrict__ out)
{
    __shared__ float red[256];
    const int tid = threadIdx.x;
    const int b = tid & (BDIM - 1);
    const int g = tid >> 7;               // 0 or 1
    float acc = 0.f;
    // lanes sweep b for fixed t: 512 B contiguous per instruction, L2-resident
    for (int t = g; t < NTILES; t += 2)
        acc += partial[t * BDIM + b];
    red[tid] = acc;
    __syncthreads();
    if (tid < BDIM)
        out[tid] = red[tid] + red[tid + BDIM];
}

extern "C" void kernel_launch(void* const* d_in, const int* in_sizes, int n_in,
                              void* d_out, int out_size, void* d_ws, size_t ws_size,
                              hipStream_t stream) {
    const float* V = (const float*)d_in[0];   // vector  [128][1024]
    const float* W = (const float*)d_in[1];   // interactions [1024][1024]
    float* out = (float*)d_out;               // [128]
    float* partial = (float*)d_ws;            // [528][128] floats = 270336 B

    potts_stage1<<<dim3(NTILES), dim3(256), 0, stream>>>(V, W, partial);
    potts_stage2<<<dim3(1), dim3(256), 0, stream>>>(partial, out);
}

// Round 3
// 77.267 us; speedup vs baseline: 1.6981x; 1.6981x over previous
//
#include <hip/hip_runtime.h>

#define NDIM 1024
#define BDIM 128
#define TS 32
#define NT (NDIM / TS)                 // 32
#define NTILES (NT * (NT + 1) / 2)     // 528 upper-tri tiles

// d_out is poisoned 0xAA before every call; zero it so tile blocks can atomicAdd.
__global__ __launch_bounds__(128) void potts_zero(float* __restrict__ out) {
    out[threadIdx.x] = 0.0f;
}

// One block per upper-tri 32x32 tile of W. Per tile row i:
//   sum_j W_ij * (q_i + r_i * v_bj) = q_i * RS_i + r_i * (sum_j W_ij * v_bj)
// RS_i = masked row sum (b-independent). This is 1 MAC per W element.
// Lane layout: lane l handles b0=l and b1=l+64 (so each broadcast wt read
// feeds 8 FMAs); wave w handles tile rows [w*8, w*8+8).
__global__ __launch_bounds__(256) void potts_tile(
    const float* __restrict__ V,      // [128][1024]
    const float* __restrict__ W,      // [1024][1024]
    float* __restrict__ out)          // [128], pre-zeroed
{
    const int t = blockIdx.x;
    int ti = 0, rem = t;
    while (rem >= NT - ti) { rem -= NT - ti; ++ti; }   // scalar decode, <=32 iters
    const int tj = ti + rem;
    const int I0 = ti * TS, J0 = tj * TS;
    const bool diag = (ti == tj);

    __shared__ float wt[TS][36];      // pad->36: rows 16B-aligned, banks balanced
    __shared__ float rs[TS];          // masked row sums
    __shared__ float red[4][BDIM];

    const int tid = threadIdx.x;
    const int w = tid >> 6;           // wave id -> i-range [w*8, w*8+8)
    const int l = tid & 63;
    const int b0 = l, b1 = l + 64;

    // ---- stage masked W tile + row sums (shfl-reduce within row's 8 lanes)
    {
        const int r = tid >> 3, c4 = (tid & 7) * 4;
        float4 w4 = *(const float4*)(W + (size_t)(I0 + r) * NDIM + (J0 + c4));
        if (diag) {                    // triu: keep j >= i
            if (c4 + 0 < r) w4.x = 0.0f;
            if (c4 + 1 < r) w4.y = 0.0f;
            if (c4 + 2 < r) w4.z = 0.0f;
            if (c4 + 3 < r) w4.w = 0.0f;
        }
        *(float4*)(&wt[r][c4]) = w4;
        float rsum = (w4.x + w4.y) + (w4.z + w4.w);
        rsum += __shfl_xor(rsum, 1);
        rsum += __shfl_xor(rsum, 2);
        rsum += __shfl_xor(rsum, 4);
        if ((tid & 7) == 0) rs[r] = rsum;
    }

    // ---- per-lane V slices straight from global (V = 512 KB, L2-resident)
    float4 vj0[8], vj1[8];
    {
        const float* p0 = V + (size_t)b0 * NDIM + J0;
        const float* p1 = V + (size_t)b1 * NDIM + J0;
#pragma unroll
        for (int j4 = 0; j4 < 8; ++j4) {
            vj0[j4] = *(const float4*)(p0 + 4 * j4);
            vj1[j4] = *(const float4*)(p1 + 4 * j4);
        }
    }
    float q0[8], r0[8], q1[8], r1[8];
    {
        const float* p0 = V + (size_t)b0 * NDIM + I0 + w * 8;
        const float* p1 = V + (size_t)b1 * NDIM + I0 + w * 8;
        const float4 a0 = *(const float4*)(p0), a1 = *(const float4*)(p0 + 4);
        const float4 c0 = *(const float4*)(p1), c1 = *(const float4*)(p1 + 4);
        const float va[8] = {a0.x, a0.y, a0.z, a0.w, a1.x, a1.y, a1.z, a1.w};
        const float vc[8] = {c0.x, c0.y, c0.z, c0.w, c1.x, c1.y, c1.z, c1.w};
#pragma unroll
        for (int k = 0; k < 8; ++k) {
            q0[k] = 1.0f - va[k]; r0[k] = 2.0f * va[k] - 1.0f;
            q1[k] = 1.0f - vc[k]; r1[k] = 2.0f * vc[k] - 1.0f;
        }
    }

    __syncthreads();

    float acc0 = 0.0f, acc1 = 0.0f;
#pragma unroll
    for (int k = 0; k < 8; ++k) {
        const float* wrow = &wt[w * 8 + k][0];
        float pa0 = 0.f, pb0 = 0.f, pa1 = 0.f, pb1 = 0.f;  // 4 indep FMA chains
#pragma unroll
        for (int j4 = 0; j4 < 8; j4 += 2) {
            const float4 wa = *(const float4*)(wrow + 4 * j4);      // uniform -> broadcast
            const float4 wb = *(const float4*)(wrow + 4 * j4 + 4);
            pa0 = fmaf(wa.x, vj0[j4].x, pa0);
            pa0 = fmaf(wa.y, vj0[j4].y, pa0);
            pa0 = fmaf(wa.z, vj0[j4].z, pa0);
            pa0 = fmaf(wa.w, vj0[j4].w, pa0);
            pa1 = fmaf(wa.x, vj1[j4].x, pa1);
            pa1 = fmaf(wa.y, vj1[j4].y, pa1);
            pa1 = fmaf(wa.z, vj1[j4].z, pa1);
            pa1 = fmaf(wa.w, vj1[j4].w, pa1);
            pb0 = fmaf(wb.x, vj0[j4 + 1].x, pb0);
            pb0 = fmaf(wb.y, vj0[j4 + 1].y, pb0);
            pb0 = fmaf(wb.z, vj0[j4 + 1].z, pb0);
            pb0 = fmaf(wb.w, vj0[j4 + 1].w, pb0);
            pb1 = fmaf(wb.x, vj1[j4 + 1].x, pb1);
            pb1 = fmaf(wb.y, vj1[j4 + 1].y, pb1);
            pb1 = fmaf(wb.z, vj1[j4 + 1].z, pb1);
            pb1 = fmaf(wb.w, vj1[j4 + 1].w, pb1);
        }
        const float rsk = rs[w * 8 + k];
        const float rv0 = pa0 + pb0, rv1 = pa1 + pb1;
        acc0 = fmaf(q0[k], rsk, acc0);
        acc0 = fmaf(r0[k], rv0, acc0);
        acc1 = fmaf(q1[k], rsk, acc1);
        acc1 = fmaf(r1[k], rv1, acc1);
    }

    red[w][b0] = acc0;
    red[w][b1] = acc1;
    __syncthreads();
    if (tid < BDIM) {
        const float s = (red[0][tid] + red[1][tid]) + (red[2][tid] + red[3][tid]);
        atomicAdd(&out[tid], s);   // 528 adds/address over ~5us: negligible contention
    }
}

extern "C" void kernel_launch(void* const* d_in, const int* in_sizes, int n_in,
                              void* d_out, int out_size, void* d_ws, size_t ws_size,
                              hipStream_t stream) {
    const float* V = (const float*)d_in[0];
    const float* W = (const float*)d_in[1];
    float* out = (float*)d_out;

    potts_zero<<<dim3(1), dim3(128), 0, stream>>>(out);
    potts_tile<<<dim3(NTILES), dim3(256), 0, stream>>>(V, W, out);
}

// Round 4
// 64.180 us; speedup vs baseline: 2.0443x; 1.2039x over previous
//
#include <hip/hip_runtime.h>

#define NDIM 1024
#define BDIM 128
#define TS 32
#define NT (NDIM / TS)                 // 32
#define NTILES (NT * (NT + 1) / 2)     // 528 upper-tri tiles

// One block per upper-tri 32x32 tile. Per tile row i (masked to triu):
//   contribution(b) = q_bi * RS_i + r_bi * (sum_j W_ij * v_bj)
// with q=1-v, r=2v-1, RS_i = masked row sum. 1 MAC per W element.
// Lane l owns b0=l, b1=l+64; wave w owns tile rows [8w, 8w+8).
__global__ __launch_bounds__(256) void potts_main(
    const float* __restrict__ V,      // [128][1024]
    const float* __restrict__ W,      // [1024][1024]
    float* __restrict__ partial)      // [NTILES][128]
{
    const int t = blockIdx.x;
    int ti = 0, rem = t;
    while (rem >= NT - ti) { rem -= NT - ti; ++ti; }
    const int tj = ti + rem;
    const int I0 = ti * TS, J0 = tj * TS;
    const bool diag = (ti == tj);

    __shared__ float wt[TS][36];        // rows 144 B (16B-aligned); broadcast reads
    __shared__ float rs[TS];            // masked row sums
    __shared__ float vjt[TS][130];      // V[:,J0+j] transposed: [j][b]; 2-way-free banks
    __shared__ float vit[TS][130];      // V[:,I0+i] transposed
    __shared__ float red[4][BDIM];

    const int tid = threadIdx.x;
    const int w = tid >> 6;
    const int l = tid & 63;

    // ---- stage masked W tile (coalesced float4) + row sums via shfl
    {
        const int r = tid >> 3, c4 = (tid & 7) * 4;
        float4 w4 = *(const float4*)(W + (size_t)(I0 + r) * NDIM + (J0 + c4));
        if (diag) {                      // triu: keep j >= i
            if (c4 + 0 < r) w4.x = 0.0f;
            if (c4 + 1 < r) w4.y = 0.0f;
            if (c4 + 2 < r) w4.z = 0.0f;
            if (c4 + 3 < r) w4.w = 0.0f;
        }
        *(float4*)(&wt[r][c4]) = w4;
        float rsum = (w4.x + w4.y) + (w4.z + w4.w);
        rsum += __shfl_xor(rsum, 1);
        rsum += __shfl_xor(rsum, 2);
        rsum += __shfl_xor(rsum, 4);
        if ((tid & 7) == 0) rs[r] = rsum;
    }

    // ---- stage V slices transposed: coalesced float4 global reads,
    //      scalar LDS writes (2-way bank aliasing only -> free)
    for (int it = 0; it < 4; ++it) {
        const int fid = tid + 256 * it;       // 1024 float4s per slice
        const int b = fid >> 3, k4 = (fid & 7) * 4;
        const float4 a = *(const float4*)(V + (size_t)b * NDIM + J0 + k4);
        vjt[k4 + 0][b] = a.x; vjt[k4 + 1][b] = a.y;
        vjt[k4 + 2][b] = a.z; vjt[k4 + 3][b] = a.w;
        const float4 c = *(const float4*)(V + (size_t)b * NDIM + I0 + k4);
        vit[k4 + 0][b] = c.x; vit[k4 + 1][b] = c.y;
        vit[k4 + 2][b] = c.z; vit[k4 + 3][b] = c.w;
    }
    __syncthreads();

    // ---- per-lane vj registers (2-way-free LDS reads)
    float vj0[TS], vj1[TS];
#pragma unroll
    for (int j = 0; j < TS; ++j) {
        vj0[j] = vjt[j][l];
        vj1[j] = vjt[j][l + 64];
    }

    float acc0 = 0.0f, acc1 = 0.0f;
#pragma unroll
    for (int k = 0; k < 8; ++k) {
        const int i = 8 * w + k;
        const float vi0 = vit[i][l], vi1 = vit[i][l + 64];
        const float q0 = 1.0f - vi0, r0 = 2.0f * vi0 - 1.0f;
        const float q1 = 1.0f - vi1, r1 = 2.0f * vi1 - 1.0f;
        const float* wrow = &wt[i][0];
        float za0 = 0.f, zb0 = 0.f, za1 = 0.f, zb1 = 0.f;
#pragma unroll
        for (int j4 = 0; j4 < 8; j4 += 2) {
            const float4 wa = *(const float4*)(wrow + 4 * j4);     // broadcast
            const float4 wb = *(const float4*)(wrow + 4 * j4 + 4); // broadcast
            za0 = fmaf(wa.x, vj0[4 * j4 + 0], za0);
            za0 = fmaf(wa.y, vj0[4 * j4 + 1], za0);
            za0 = fmaf(wa.z, vj0[4 * j4 + 2], za0);
            za0 = fmaf(wa.w, vj0[4 * j4 + 3], za0);
            za1 = fmaf(wa.x, vj1[4 * j4 + 0], za1);
            za1 = fmaf(wa.y, vj1[4 * j4 + 1], za1);
            za1 = fmaf(wa.z, vj1[4 * j4 + 2], za1);
            za1 = fmaf(wa.w, vj1[4 * j4 + 3], za1);
            zb0 = fmaf(wb.x, vj0[4 * j4 + 4], zb0);
            zb0 = fmaf(wb.y, vj0[4 * j4 + 5], zb0);
            zb0 = fmaf(wb.z, vj0[4 * j4 + 6], zb0);
            zb0 = fmaf(wb.w, vj0[4 * j4 + 7], zb0);
            zb1 = fmaf(wb.x, vj1[4 * j4 + 4], zb1);
            zb1 = fmaf(wb.y, vj1[4 * j4 + 5], zb1);
            zb1 = fmaf(wb.z, vj1[4 * j4 + 6], zb1);
            zb1 = fmaf(wb.w, vj1[4 * j4 + 7], zb1);
        }
        const float rsk = rs[i];
        acc0 = fmaf(q0, rsk, acc0);
        acc0 = fmaf(r0, za0 + zb0, acc0);
        acc1 = fmaf(q1, rsk, acc1);
        acc1 = fmaf(r1, za1 + zb1, acc1);
    }

    red[w][l] = acc0;
    red[w][l + 64] = acc1;
    __syncthreads();
    if (tid < BDIM) {
        partial[t * BDIM + tid] =
            (red[0][tid] + red[1][tid]) + (red[2][tid] + red[3][tid]);
    }
}

// ---- reduce 528 tile partials -> out[b]; one block per b, latency-pipelined
__global__ __launch_bounds__(64) void potts_red(
    const float* __restrict__ partial, float* __restrict__ out)
{
    const int b = blockIdx.x;
    const int lane = threadIdx.x;
    float a0 = 0.f, a1 = 0.f;
    int t = lane;
#pragma unroll 4
    for (; t + 64 < NTILES; t += 128) {       // 2 indep chains, 9 loads/lane total
        a0 += partial[t * BDIM + b];
        a1 += partial[(t + 64) * BDIM + b];
    }
    if (t < NTILES) a0 += partial[t * BDIM + b];
    float a = a0 + a1;
#pragma unroll
    for (int off = 32; off > 0; off >>= 1)
        a += __shfl_down(a, off);
    if (lane == 0) out[b] = a;
}

extern "C" void kernel_launch(void* const* d_in, const int* in_sizes, int n_in,
                              void* d_out, int out_size, void* d_ws, size_t ws_size,
                              hipStream_t stream) {
    const float* V = (const float*)d_in[0];
    const float* W = (const float*)d_in[1];
    float* out = (float*)d_out;
    float* partial = (float*)d_ws;            // 528*128*4 = 270336 B

    potts_main<<<dim3(NTILES), dim3(256), 0, stream>>>(V, W, partial);
    potts_red<<<dim3(BDIM), dim3(64), 0, stream>>>(partial, out);
}